// Round 10
// baseline (280.466 us; speedup 1.0000x reference)
//
#include <hip/hip_runtime.h>
#include <math.h>

#define NS 512
#define NF 40
#define ROWS_OUT 513
#define DTC (1.0f / 512.0f)
#define PLANE 512

typedef short bf16x8 __attribute__((ext_vector_type(8)));
typedef float f32x4 __attribute__((ext_vector_type(4)));

// ws layout (floats):
//   [0..511]      w[m]            (device-computed, fp64)
//   [512..1023]   cumw2[t]        (device-computed, fp64 prefix)
//   [1024..1343]  per-forward constants, 8 per n (see const_kernel)
//   [1344.. +256K] W Toeplitz bf16 512x512 row-major (if ws_size permits)
#define W_BYTES_NEEDED (1344u * 4u + 512u * 512u * 2u)

__device__ __forceinline__ unsigned short f2bf(float x) {
    unsigned int u = __float_as_uint(x);
    return (unsigned short)((u + 0x7FFFu + ((u >> 16) & 1u)) >> 16);   // RNE
}

__global__ __launch_bounds__(64) void const_kernel(
    const float* __restrict__ F0, const float* __restrict__ alphas,
    const float* __restrict__ rhos, const float* __restrict__ nus,
    const float* __restrict__ tau, const float* __restrict__ L,
    const float* __restrict__ Lam, float* __restrict__ ws)
{
    __shared__ double wd[NS];
    __shared__ float omega0[NF];
    __shared__ float vs_s[NF];
    int n = threadIdx.x;
    {
        const double g06 = 1.4891922488128171;      // Gamma(0.6)
        const double dta = pow(512.0, 0.4);         // DT^ALPHA
        #pragma unroll
        for (int k = 0; k < 8; ++k) {
            int m = n * 8 + k;
            double wv = (pow((double)m + 1.0, 0.6) - pow((double)m, 0.6)) * (1.0 / 0.6) * dta / g06;
            wd[m] = wv;
            ws[m] = (float)wv;
        }
    }
    if (n < NF) {
        float f0 = F0[n];
        float vs = alphas[n] * sqrtf(fabsf(f0 + 0.02f));
        vs_s[n] = vs;
        omega0[n] = tau[n] * vs / (1.0f + tau[n] * f0);
    }
    __syncthreads();
    if (n == 0) {
        double acc = 0.0;
        for (int m = 0; m < NS; ++m) { acc += wd[m] * wd[m]; ws[NS + m] = (float)acc; }
    }
    if (n < NF) {
        float s = 0.0f;
        for (int j = 0; j < NF; ++j) s += Lam[n * NF + j] * omega0[j];
        float vs = vs_s[n];
        float mu0 = -vs * s;
        float rho = rhos[n], nu = nus[n];
        float* c = ws + 1024 + n * 8;
        c[0] = vs * L[n * 3 + 0];
        c[1] = vs * L[n * 3 + 1];
        c[2] = vs * L[n * 3 + 2];
        c[3] = nu * rho / fmaxf(vs, 1e-30f);
        c[4] = nu * sqrtf(fmaxf(1.0f - rho * rho, 0.0f));
        c[5] = 0.5f * nu * nu * DTC;
        c[6] = mu0 * DTC;
        c[7] = F0[n];
    }
}

// Build W[t][s] = bf16(w[t-s]) for s<=t else 0; 512 rows x 512 cols, row-major.
__global__ __launch_bounds__(128) void toeplitz_kernel(float* __restrict__ ws)
{
    int t = blockIdx.x;
    int s0 = threadIdx.x * 4;
    ushort4 v;
    v.x = (s0 + 0 <= t) ? f2bf(ws[t - s0 - 0]) : (unsigned short)0;
    v.y = (s0 + 1 <= t) ? f2bf(ws[t - s0 - 1]) : (unsigned short)0;
    v.z = (s0 + 2 <= t) ? f2bf(ws[t - s0 - 2]) : (unsigned short)0;
    v.w = (s0 + 3 <= t) ? f2bf(ws[t - s0 - 3]) : (unsigned short)0;
    ushort4* W = (ushort4*)((unsigned short*)(ws + 1344) + (size_t)t * 512);
    W[threadIdx.x] = v;
}

// ---- wave64 inclusive scan via DPP (pure VALU) ----
template<int CTRL, int RM>
__device__ __forceinline__ float dpp_add(float v) {
    int t = __builtin_amdgcn_update_dpp(0, __float_as_int(v), CTRL, RM, 0xf, true);
    return v + __int_as_float(t);
}
__device__ __forceinline__ float wave_iscan(float v) {
    v = dpp_add<0x111, 0xf>(v);
    v = dpp_add<0x112, 0xf>(v);
    v = dpp_add<0x114, 0xf>(v);
    v = dpp_add<0x118, 0xf>(v);
    v = dpp_add<0x142, 0xa>(v);
    v = dpp_add<0x143, 0xc>(v);
    return v;
}

__device__ __forceinline__ void fma4(float4& acc, float c, const float4& v) {
    acc.x = fmaf(c, v.x, acc.x);
    acc.y = fmaf(c, v.y, acc.y);
    acc.z = fmaf(c, v.z, acc.z);
    acc.w = fmaf(c, v.w, acc.w);
}

// ================= MFMA variant: 1 path/block, planes[t][4] =================
__global__ __launch_bounds__(256, 8) void path_kernel_mfma(
    const float* __restrict__ dz, const float* __restrict__ ws,
    float* __restrict__ out)
{
    __shared__ float planes[NS * 4];     //  8192 B: fbm4, [t][c] fp32
    __shared__ float ustage[64 * 41];    // 10496 B: dzb (phase B) / chunk (C/D)

    int tid = threadIdx.x;
    int lane = tid & 63;
    int wv = __builtin_amdgcn_readfirstlane(tid >> 6);
    int p = blockIdx.x;
    const float4* dzg = (const float4*)dz + (size_t)p * NS;

    // ---- stage dz as bf16, component-major dzb[c][k] (aliases chunk LDS)
    unsigned short* dzb = (unsigned short*)ustage;
    {
        int k2 = tid * 2;
        float4 da = dzg[k2], db = dzg[k2 + 1];
        unsigned int* d32 = (unsigned int*)dzb;
        d32[0 * 256 + tid] = (unsigned int)f2bf(da.x) | ((unsigned int)f2bf(db.x) << 16);
        d32[1 * 256 + tid] = (unsigned int)f2bf(da.y) | ((unsigned int)f2bf(db.y) << 16);
        d32[2 * 256 + tid] = (unsigned int)f2bf(da.z) | ((unsigned int)f2bf(db.z) << 16);
        d32[3 * 256 + tid] = (unsigned int)f2bf(da.w) | ((unsigned int)f2bf(db.w) << 16);
    }
    __syncthreads();

    // ---- Phase B on the matrix pipe: fbm4 = W(512x512 tri) x dz(512x4).
    // mfma_f32_16x16x32_bf16; A row = lane&15, k = (lane>>4)*8+i (A from W in
    // L2: exactly one 64B line per row per K-step, shared by all blocks);
    // B col = lane&15 (cols 4..15 duplicate c&3 -> discarded), same k map;
    // D (verified m89/m91): col = lane&15, row = (lane>>4)*4 + reg.
    // Wave wv owns M-tiles {wv, wv+4, ..., wv+28}; triangular K-skip per tile.
    {
        const unsigned short* W = (const unsigned short*)(ws + 1344);
        int arow = lane & 15, ksub = lane >> 4;
        f32x4 acc[8];
        #pragma unroll
        for (int j = 0; j < 8; ++j) acc[j] = (f32x4){0.f, 0.f, 0.f, 0.f};
        const unsigned short* bbase = dzb + (lane & 3) * 512 + ksub * 8;
        #pragma unroll 1
        for (int k = 0; k < 16; ++k) {
            bf16x8 bf = *(const bf16x8*)(bbase + k * 32);
            #pragma unroll
            for (int j = 0; j < 8; ++j) {
                int m = wv + 4 * j;
                if (k <= ((16 * m + 15) >> 5)) {     // wave-uniform scalar branch
                    bf16x8 af = *(const bf16x8*)(W + (size_t)(16 * m + arow) * NS + k * 32 + ksub * 8);
                    acc[j] = __builtin_amdgcn_mfma_f32_16x16x32_bf16(af, bf, acc[j], 0, 0, 0);
                }
            }
        }
        if (arow < 4) {                              // cols 0..3 hold fbm4[t][c]
            #pragma unroll
            for (int j = 0; j < 8; ++j) {
                int m = wv + 4 * j;
                #pragma unroll
                for (int r = 0; r < 4; ++r)
                    planes[(16 * m + ksub * 4 + r) * 4 + arow] = acc[j][r];
            }
        }
    }

    float carry[10];
    #pragma unroll
    for (int j = 0; j < 10; ++j) carry[j] = 0.0f;

    float* outP = out + (size_t)p * (ROWS_OUT * NF);
    if (tid < NF) outP[tid] = ws[1024 + tid * 8 + 7];               // row 0 = F0

    __syncthreads();   // planes ready; all dzb reads done -> chunk may reuse LDS

    // ---- Phase C/D: per chunk of 64 t (lane = t): dF, DPP scan, transpose, store.
    float* chunk = ustage;
    const float* cwg = ws + NS;
    const float4* planes4 = (const float4*)planes;
    for (int cix = 0; cix < 8; ++cix) {
        int t = cix * 64 + lane;
        float cw = cwg[t];
        float4 f4 = planes4[t];
        float fx = f4.x, fy = f4.y, fz = f4.z, fw = f4.w;
        float4 d = dzg[t];
        #pragma unroll
        for (int j = 0; j < 10; ++j) {
            int n = wv * 10 + j;
            const float* c = ws + 1024 + n * 8;
            float cC0 = c[0], cC1 = c[1], cC2 = c[2], q = c[3];
            float cA3 = c[4], ca = c[5], cm0 = c[6], f0 = c[7];
            float dotf = fx * cC0 + fy * cC1 + fz * cC2;
            float arg = fmaf(q, dotf, fmaf(cA3, fw, -ca * cw));
            float uv = __expf(arg);
            float dotc = d.x * cC0 + d.y * cC1 + d.z * cC2;
            float dF = uv * fmaf(cm0, uv, dotc);
            float v = wave_iscan(dF) + carry[j];
            carry[j] = __int_as_float(__builtin_amdgcn_readlane(__float_as_int(v), 63));
            chunk[lane * 41 + n] = v + f0;
        }
        __syncthreads();
        float* o = outP + NF + cix * (64 * NF);
        #pragma unroll
        for (int k = 0; k < 10; ++k) {
            int f = tid + k * 256;
            __builtin_nontemporal_store(chunk[f + f / 40], o + f);
        }
        __syncthreads();
    }
}

// ================= Fallback: R9 vector kernel, verbatim =================
__global__ __launch_bounds__(256, 8) void path_kernel(
    const float* __restrict__ dz, const float* __restrict__ ws,
    float* __restrict__ out)
{
    __shared__ float planes[4 * PLANE];
    __shared__ float ustage[64 * 41];

    int tid = threadIdx.x;
    int lane = tid & 63;
    int wv = __builtin_amdgcn_readfirstlane(tid >> 6);
    int p = blockIdx.x;
    const float4* dzg = (const float4*)dz + (size_t)p * NS;

    float* wp = ustage;
    for (int i = tid; i < 768; i += 256) wp[i] = (i < 256) ? 0.0f : ws[i - 256];
    __syncthreads();

    {
        int role = (wv + p) & 3;
        int half = role >> 1;
        int seg  = role & 1;
        int i = half * 64 + lane;
        int span = half ? 64 : 32;
        int g0 = seg * span, g1 = g0 + span;
        const float4* wp4 = (const float4*)wp;
        float4 a0 = make_float4(0.f, 0.f, 0.f, 0.f);
        float4 a1 = a0, a2 = a0, a3 = a0;
        #pragma unroll 2
        for (int g = g0; g < g1; ++g) {
            float4 d0 = dzg[4 * g + 0];
            float4 d1 = dzg[4 * g + 1];
            float4 d2 = dzg[4 * g + 2];
            float4 d3 = dzg[4 * g + 3];
            float4 lo = wp4[63 + i - g];
            float4 hi = wp4[64 + i - g];
            fma4(a0, hi.x, d0); fma4(a1, hi.y, d0); fma4(a2, hi.z, d0); fma4(a3, hi.w, d0);
            fma4(a0, lo.w, d1); fma4(a1, hi.x, d1); fma4(a2, hi.y, d1); fma4(a3, hi.z, d1);
            fma4(a0, lo.z, d2); fma4(a1, lo.w, d2); fma4(a2, hi.x, d2); fma4(a3, hi.y, d2);
            fma4(a0, lo.y, d3); fma4(a1, lo.z, d3); fma4(a2, lo.w, d3); fma4(a3, hi.x, d3);
        }
        if (seg == 1) {
            ((float4*)(planes + 0 * PLANE))[i] = make_float4(a0.x, a1.x, a2.x, a3.x);
            ((float4*)(planes + 1 * PLANE))[i] = make_float4(a0.y, a1.y, a2.y, a3.y);
            ((float4*)(planes + 2 * PLANE))[i] = make_float4(a0.z, a1.z, a2.z, a3.z);
            ((float4*)(planes + 3 * PLANE))[i] = make_float4(a0.w, a1.w, a2.w, a3.w);
        }
        __syncthreads();
        if (seg == 0) {
            float4* q0 = &((float4*)(planes + 0 * PLANE))[i];
            float4* q1 = &((float4*)(planes + 1 * PLANE))[i];
            float4* q2 = &((float4*)(planes + 2 * PLANE))[i];
            float4* q3 = &((float4*)(planes + 3 * PLANE))[i];
            float4 c0 = *q0, c1 = *q1, c2 = *q2, c3 = *q3;
            c0.x += a0.x; c0.y += a1.x; c0.z += a2.x; c0.w += a3.x;
            c1.x += a0.y; c1.y += a1.y; c1.z += a2.y; c1.w += a3.y;
            c2.x += a0.z; c2.y += a1.z; c2.z += a2.z; c2.w += a3.z;
            c3.x += a0.w; c3.y += a1.w; c3.z += a2.w; c3.w += a3.w;
            *q0 = c0; *q1 = c1; *q2 = c2; *q3 = c3;
        }
        __syncthreads();
    }

    float carry[10];
    #pragma unroll
    for (int j = 0; j < 10; ++j) carry[j] = 0.0f;

    float* outP = out + (size_t)p * (ROWS_OUT * NF);
    if (tid < NF) outP[tid] = ws[1024 + tid * 8 + 7];

    float* chunk = ustage;
    const float* cwg = ws + NS;
    for (int cix = 0; cix < 8; ++cix) {
        int t = cix * 64 + lane;
        float cw = cwg[t];
        float fx = planes[t], fy = planes[PLANE + t];
        float fz = planes[2 * PLANE + t], fw = planes[3 * PLANE + t];
        float4 d = dzg[t];
        #pragma unroll
        for (int j = 0; j < 10; ++j) {
            int n = wv * 10 + j;
            const float* c = ws + 1024 + n * 8;
            float cC0 = c[0], cC1 = c[1], cC2 = c[2], q = c[3];
            float cA3 = c[4], ca = c[5], cm0 = c[6], f0 = c[7];
            float dotf = fx * cC0 + fy * cC1 + fz * cC2;
            float arg = fmaf(q, dotf, fmaf(cA3, fw, -ca * cw));
            float uv = __expf(arg);
            float dotc = d.x * cC0 + d.y * cC1 + d.z * cC2;
            float dF = uv * fmaf(cm0, uv, dotc);
            float v = wave_iscan(dF) + carry[j];
            carry[j] = __int_as_float(__builtin_amdgcn_readlane(__float_as_int(v), 63));
            chunk[lane * 41 + n] = v + f0;
        }
        __syncthreads();
        float* o = outP + NF + cix * (64 * NF);
        #pragma unroll
        for (int k = 0; k < 10; ++k) {
            int f = tid + k * 256;
            __builtin_nontemporal_store(chunk[f + f / 40], o + f);
        }
        __syncthreads();
    }
}

extern "C" void kernel_launch(void* const* d_in, const int* in_sizes, int n_in,
                              void* d_out, int out_size, void* d_ws, size_t ws_size,
                              hipStream_t stream) {
    const float* dz   = (const float*)d_in[0];
    const float* F0   = (const float*)d_in[1];
    const float* alph = (const float*)d_in[2];
    const float* rhos = (const float*)d_in[3];
    const float* nus  = (const float*)d_in[4];
    const float* tau  = (const float*)d_in[5];
    const float* L    = (const float*)d_in[6];
    const float* Lam  = (const float*)d_in[7];
    float* ws = (float*)d_ws;
    float* out = (float*)d_out;

    int n_paths = in_sizes[0] / (NS * 4);

    const_kernel<<<1, 64, 0, stream>>>(F0, alph, rhos, nus, tau, L, Lam, ws);
    if (ws_size >= (size_t)W_BYTES_NEEDED) {
        toeplitz_kernel<<<512, 128, 0, stream>>>(ws);
        path_kernel_mfma<<<n_paths, 256, 0, stream>>>(dz, ws, out);
    } else {
        path_kernel<<<n_paths, 256, 0, stream>>>(dz, ws, out);
    }
}

// Round 11
// 248.291 us; speedup vs baseline: 1.1296x; 1.1296x over previous
//
#include <hip/hip_runtime.h>
#include <math.h>

#define NS 512
#define NF 40
#define ROWS_OUT 513
#define DTC (1.0f / 512.0f)
#define PLANE 512
#define WOFF 132416          // float offset of fbm4 planes region (1344 + 512*512*2/4)
#define LOG2E 1.4426950408889634f

typedef short bf16x8 __attribute__((ext_vector_type(8)));
typedef float f32x4 __attribute__((ext_vector_type(4)));

// ws layout (floats):
//   [0..511]       w[m]           (device fp64)
//   [512..1023]    cumw2[t]       (device fp64 prefix)
//   [1024..1343]   per-forward constants, 8 per n (q/cA3/ca pre-scaled by log2e)
//   [1344..132415] W Toeplitz bf16 512x512 row-major
//   [WOFF..]       fbm4 planes_g[path][comp][t] fp32 (if ws_size permits)

__device__ __forceinline__ unsigned short f2bf(float x) {
    unsigned int u = __float_as_uint(x);
    return (unsigned short)((u + 0x7FFFu + ((u >> 16) & 1u)) >> 16);   // RNE
}

__global__ __launch_bounds__(64) void const_kernel(
    const float* __restrict__ F0, const float* __restrict__ alphas,
    const float* __restrict__ rhos, const float* __restrict__ nus,
    const float* __restrict__ tau, const float* __restrict__ L,
    const float* __restrict__ Lam, float* __restrict__ ws)
{
    __shared__ double wd[NS];
    __shared__ float omega0[NF];
    __shared__ float vs_s[NF];
    int n = threadIdx.x;
    {
        const double g06 = 1.4891922488128171;      // Gamma(0.6)
        const double dta = pow(512.0, 0.4);         // DT^ALPHA
        #pragma unroll
        for (int k = 0; k < 8; ++k) {
            int m = n * 8 + k;
            double wv = (pow((double)m + 1.0, 0.6) - pow((double)m, 0.6)) * (1.0 / 0.6) * dta / g06;
            wd[m] = wv;
            ws[m] = (float)wv;
        }
    }
    if (n < NF) {
        float f0 = F0[n];
        float vs = alphas[n] * sqrtf(fabsf(f0 + 0.02f));
        vs_s[n] = vs;
        omega0[n] = tau[n] * vs / (1.0f + tau[n] * f0);
    }
    __syncthreads();
    if (n == 0) {
        double acc = 0.0;
        for (int m = 0; m < NS; ++m) { acc += wd[m] * wd[m]; ws[NS + m] = (float)acc; }
    }
    if (n < NF) {
        float s = 0.0f;
        for (int j = 0; j < NF; ++j) s += Lam[n * NF + j] * omega0[j];
        float vs = vs_s[n];
        float mu0 = -vs * s;
        float rho = rhos[n], nu = nus[n];
        float* c = ws + 1024 + n * 8;
        c[0] = vs * L[n * 3 + 0];
        c[1] = vs * L[n * 3 + 1];
        c[2] = vs * L[n * 3 + 2];
        // q, cA3, ca feed ONLY the exp argument: bake log2(e) in, use exp2f.
        c[3] = (nu * rho / fmaxf(vs, 1e-30f)) * LOG2E;
        c[4] = (nu * sqrtf(fmaxf(1.0f - rho * rho, 0.0f))) * LOG2E;
        c[5] = (0.5f * nu * nu * DTC) * LOG2E;
        c[6] = mu0 * DTC;
        c[7] = F0[n];
    }
}

// Build W[t][s] = bf16(w[t-s]) for s<=t else 0; 512x512 row-major.
__global__ __launch_bounds__(128) void toeplitz_kernel(float* __restrict__ ws)
{
    int t = blockIdx.x;
    int s0 = threadIdx.x * 4;
    ushort4 v;
    v.x = (s0 + 0 <= t) ? f2bf(ws[t - s0 - 0]) : (unsigned short)0;
    v.y = (s0 + 1 <= t) ? f2bf(ws[t - s0 - 1]) : (unsigned short)0;
    v.z = (s0 + 2 <= t) ? f2bf(ws[t - s0 - 2]) : (unsigned short)0;
    v.w = (s0 + 3 <= t) ? f2bf(ws[t - s0 - 3]) : (unsigned short)0;
    ushort4* W = (ushort4*)((unsigned short*)(ws + 1344) + (size_t)t * 512);
    W[threadIdx.x] = v;
}

// ---- wave64 inclusive scan via DPP (pure VALU) ----
template<int CTRL, int RM>
__device__ __forceinline__ float dpp_add(float v) {
    int t = __builtin_amdgcn_update_dpp(0, __float_as_int(v), CTRL, RM, 0xf, true);
    return v + __int_as_float(t);
}
__device__ __forceinline__ float wave_iscan(float v) {
    v = dpp_add<0x111, 0xf>(v);
    v = dpp_add<0x112, 0xf>(v);
    v = dpp_add<0x114, 0xf>(v);
    v = dpp_add<0x118, 0xf>(v);
    v = dpp_add<0x142, 0xa>(v);
    v = dpp_add<0x143, 0xc>(v);
    return v;
}

__device__ __forceinline__ void fma4(float4& acc, float c, const float4& v) {
    acc.x = fmaf(c, v.x, acc.x);
    acc.y = fmaf(c, v.y, acc.y);
    acc.z = fmaf(c, v.z, acc.z);
    acc.w = fmaf(c, v.w, acc.w);
}

// ============ Kernel GB: fbm4 for 4 paths/block via batched MFMA ============
// B operand uses all 16 cols = 4 paths x 4 comps -> W (A) traffic amortized 4x
// vs R10 (whose 1-path variant was L2-BW-bound). Fragment mapping verified
// on-device in R10 (passed, absmax unchanged).
__global__ __launch_bounds__(256, 4) void gemmB_kernel(
    const float* __restrict__ dz, float* __restrict__ ws)
{
    __shared__ unsigned short dzb[16 * 520];   // [col=pl*4+comp][k] bf16, padded stride
    int tid = threadIdx.x;
    int lane = tid & 63;
    int wv = __builtin_amdgcn_readfirstlane(tid >> 6);
    int p0 = blockIdx.x * 4;

    // wave wv stages path p0+wv as bf16 pairs into its 4 component columns
    {
        const float4* dzg = (const float4*)dz + (size_t)(p0 + wv) * NS;
        unsigned int* d32 = (unsigned int*)dzb;
        #pragma unroll
        for (int it = 0; it < 4; ++it) {
            int k2 = it * 128 + lane * 2;
            float4 da = dzg[k2], db = dzg[k2 + 1];
            int o = it * 64 + lane;            // u32 pair index (k2/2)
            d32[(wv * 4 + 0) * 260 + o] = (unsigned int)f2bf(da.x) | ((unsigned int)f2bf(db.x) << 16);
            d32[(wv * 4 + 1) * 260 + o] = (unsigned int)f2bf(da.y) | ((unsigned int)f2bf(db.y) << 16);
            d32[(wv * 4 + 2) * 260 + o] = (unsigned int)f2bf(da.z) | ((unsigned int)f2bf(db.z) << 16);
            d32[(wv * 4 + 3) * 260 + o] = (unsigned int)f2bf(da.w) | ((unsigned int)f2bf(db.w) << 16);
        }
    }
    __syncthreads();

    const unsigned short* W = (const unsigned short*)(ws + 1344);
    int col = lane & 15, ksub = lane >> 4;     // A row / B-D col = lane&15; k-sub = lane>>4
    f32x4 acc[8];
    #pragma unroll
    for (int j = 0; j < 8; ++j) acc[j] = (f32x4){0.f, 0.f, 0.f, 0.f};
    const unsigned short* bbase = dzb + col * 520 + ksub * 8;
    #pragma unroll 1
    for (int k = 0; k < 16; ++k) {
        bf16x8 bfv = *(const bf16x8*)(bbase + k * 32);
        #pragma unroll
        for (int j = 0; j < 8; ++j) {
            int m = wv + 4 * j;                // M-tile (rows 16m..16m+15)
            if (k <= ((16 * m + 15) >> 5)) {   // triangular K-skip, wave-uniform
                bf16x8 af = *(const bf16x8*)(W + (size_t)(16 * m + col) * NS + k * 32 + ksub * 8);
                acc[j] = __builtin_amdgcn_mfma_f32_16x16x32_bf16(af, bfv, acc[j], 0, 0, 0);
            }
        }
    }
    // D: col = lane&15 -> (path_local, comp); rows t0..t0+3 = 16m + ksub*4 + r
    float* pg = ws + WOFF + ((size_t)(p0 + (col >> 2)) * 4 + (col & 3)) * NS;
    #pragma unroll
    for (int j = 0; j < 8; ++j) {
        int t0 = 16 * (wv + 4 * j) + ksub * 4;
        *(float4*)(pg + t0) = make_float4(acc[j][0], acc[j][1], acc[j][2], acc[j][3]);
    }
}

// ============ Kernel CD: dF, scan, transpose, store (R9 phase C/D) ============
__global__ __launch_bounds__(256, 8) void pathCD_kernel(
    const float* __restrict__ dz, const float* __restrict__ ws,
    float* __restrict__ out)
{
    __shared__ float chunk[64 * 41];           // 10496 B only -> 8 blocks/CU

    int tid = threadIdx.x;
    int lane = tid & 63;
    int wv = __builtin_amdgcn_readfirstlane(tid >> 6);
    int p = blockIdx.x;
    const float4* dzg = (const float4*)dz + (size_t)p * NS;
    const float* pg = ws + WOFF + (size_t)p * 4 * NS;
    const float* cwg = ws + NS;

    float carry[10];
    #pragma unroll
    for (int j = 0; j < 10; ++j) carry[j] = 0.0f;

    float* outP = out + (size_t)p * (ROWS_OUT * NF);
    if (tid < NF) outP[tid] = ws[1024 + tid * 8 + 7];               // row 0 = F0

    for (int cix = 0; cix < 8; ++cix) {
        int t = cix * 64 + lane;
        float cw = cwg[t];
        float fx = pg[t], fy = pg[NS + t], fz = pg[2 * NS + t], fw = pg[3 * NS + t];
        float4 d = dzg[t];
        #pragma unroll
        for (int j = 0; j < 10; ++j) {
            int n = wv * 10 + j;
            const float* c = ws + 1024 + n * 8;
            float cC0 = c[0], cC1 = c[1], cC2 = c[2], q = c[3];
            float cA3 = c[4], ca = c[5], cm0 = c[6], f0 = c[7];
            float dotf = fx * cC0 + fy * cC1 + fz * cC2;
            float arg = fmaf(q, dotf, fmaf(cA3, fw, -ca * cw));
            float uv = exp2f(arg);                  // log2e pre-baked into q/cA3/ca
            float dotc = d.x * cC0 + d.y * cC1 + d.z * cC2;
            float dF = uv * fmaf(cm0, uv, dotc);
            float v = wave_iscan(dF) + carry[j];
            carry[j] = __int_as_float(__builtin_amdgcn_readlane(__float_as_int(v), 63));
            chunk[lane * 41 + n] = v + f0;
        }
        __syncthreads();
        float* o = outP + NF + cix * (64 * NF);
        #pragma unroll
        for (int k = 0; k < 10; ++k) {
            int f = tid + k * 256;
            __builtin_nontemporal_store(chunk[f + f / 40], o + f);
        }
        __syncthreads();
    }
}

// ================= Fallback: R9 vector kernel (exp2f-adjusted) =================
__global__ __launch_bounds__(256, 8) void path_kernel(
    const float* __restrict__ dz, const float* __restrict__ ws,
    float* __restrict__ out)
{
    __shared__ float planes[4 * PLANE];
    __shared__ float ustage[64 * 41];

    int tid = threadIdx.x;
    int lane = tid & 63;
    int wv = __builtin_amdgcn_readfirstlane(tid >> 6);
    int p = blockIdx.x;
    const float4* dzg = (const float4*)dz + (size_t)p * NS;

    float* wp = ustage;
    for (int i = tid; i < 768; i += 256) wp[i] = (i < 256) ? 0.0f : ws[i - 256];
    __syncthreads();

    {
        int role = (wv + p) & 3;
        int half = role >> 1;
        int seg  = role & 1;
        int i = half * 64 + lane;
        int span = half ? 64 : 32;
        int g0 = seg * span, g1 = g0 + span;
        const float4* wp4 = (const float4*)wp;
        float4 a0 = make_float4(0.f, 0.f, 0.f, 0.f);
        float4 a1 = a0, a2 = a0, a3 = a0;
        #pragma unroll 2
        for (int g = g0; g < g1; ++g) {
            float4 d0 = dzg[4 * g + 0];
            float4 d1 = dzg[4 * g + 1];
            float4 d2 = dzg[4 * g + 2];
            float4 d3 = dzg[4 * g + 3];
            float4 lo = wp4[63 + i - g];
            float4 hi = wp4[64 + i - g];
            fma4(a0, hi.x, d0); fma4(a1, hi.y, d0); fma4(a2, hi.z, d0); fma4(a3, hi.w, d0);
            fma4(a0, lo.w, d1); fma4(a1, hi.x, d1); fma4(a2, hi.y, d1); fma4(a3, hi.z, d1);
            fma4(a0, lo.z, d2); fma4(a1, lo.w, d2); fma4(a2, hi.x, d2); fma4(a3, hi.y, d2);
            fma4(a0, lo.y, d3); fma4(a1, lo.z, d3); fma4(a2, lo.w, d3); fma4(a3, hi.x, d3);
        }
        if (seg == 1) {
            ((float4*)(planes + 0 * PLANE))[i] = make_float4(a0.x, a1.x, a2.x, a3.x);
            ((float4*)(planes + 1 * PLANE))[i] = make_float4(a0.y, a1.y, a2.y, a3.y);
            ((float4*)(planes + 2 * PLANE))[i] = make_float4(a0.z, a1.z, a2.z, a3.z);
            ((float4*)(planes + 3 * PLANE))[i] = make_float4(a0.w, a1.w, a2.w, a3.w);
        }
        __syncthreads();
        if (seg == 0) {
            float4* q0 = &((float4*)(planes + 0 * PLANE))[i];
            float4* q1 = &((float4*)(planes + 1 * PLANE))[i];
            float4* q2 = &((float4*)(planes + 2 * PLANE))[i];
            float4* q3 = &((float4*)(planes + 3 * PLANE))[i];
            float4 c0 = *q0, c1 = *q1, c2 = *q2, c3 = *q3;
            c0.x += a0.x; c0.y += a1.x; c0.z += a2.x; c0.w += a3.x;
            c1.x += a0.y; c1.y += a1.y; c1.z += a2.y; c1.w += a3.y;
            c2.x += a0.z; c2.y += a1.z; c2.z += a2.z; c2.w += a3.z;
            c3.x += a0.w; c3.y += a1.w; c3.z += a2.w; c3.w += a3.w;
            *q0 = c0; *q1 = c1; *q2 = c2; *q3 = c3;
        }
        __syncthreads();
    }

    float carry[10];
    #pragma unroll
    for (int j = 0; j < 10; ++j) carry[j] = 0.0f;

    float* outP = out + (size_t)p * (ROWS_OUT * NF);
    if (tid < NF) outP[tid] = ws[1024 + tid * 8 + 7];

    float* chunk = ustage;
    const float* cwg = ws + NS;
    for (int cix = 0; cix < 8; ++cix) {
        int t = cix * 64 + lane;
        float cw = cwg[t];
        float fx = planes[t], fy = planes[PLANE + t];
        float fz = planes[2 * PLANE + t], fw = planes[3 * PLANE + t];
        float4 d = dzg[t];
        #pragma unroll
        for (int j = 0; j < 10; ++j) {
            int n = wv * 10 + j;
            const float* c = ws + 1024 + n * 8;
            float cC0 = c[0], cC1 = c[1], cC2 = c[2], q = c[3];
            float cA3 = c[4], ca = c[5], cm0 = c[6], f0 = c[7];
            float dotf = fx * cC0 + fy * cC1 + fz * cC2;
            float arg = fmaf(q, dotf, fmaf(cA3, fw, -ca * cw));
            float uv = exp2f(arg);
            float dotc = d.x * cC0 + d.y * cC1 + d.z * cC2;
            float dF = uv * fmaf(cm0, uv, dotc);
            float v = wave_iscan(dF) + carry[j];
            carry[j] = __int_as_float(__builtin_amdgcn_readlane(__float_as_int(v), 63));
            chunk[lane * 41 + n] = v + f0;
        }
        __syncthreads();
        float* o = outP + NF + cix * (64 * NF);
        #pragma unroll
        for (int k = 0; k < 10; ++k) {
            int f = tid + k * 256;
            __builtin_nontemporal_store(chunk[f + f / 40], o + f);
        }
        __syncthreads();
    }
}

extern "C" void kernel_launch(void* const* d_in, const int* in_sizes, int n_in,
                              void* d_out, int out_size, void* d_ws, size_t ws_size,
                              hipStream_t stream) {
    const float* dz   = (const float*)d_in[0];
    const float* F0   = (const float*)d_in[1];
    const float* alph = (const float*)d_in[2];
    const float* rhos = (const float*)d_in[3];
    const float* nus  = (const float*)d_in[4];
    const float* tau  = (const float*)d_in[5];
    const float* L    = (const float*)d_in[6];
    const float* Lam  = (const float*)d_in[7];
    float* ws = (float*)d_ws;
    float* out = (float*)d_out;

    int n_paths = in_sizes[0] / (NS * 4);
    size_t full_bytes = ((size_t)WOFF + (size_t)n_paths * 4 * NS) * 4;

    const_kernel<<<1, 64, 0, stream>>>(F0, alph, rhos, nus, tau, L, Lam, ws);
    if (ws_size >= full_bytes && (n_paths & 3) == 0) {
        toeplitz_kernel<<<512, 128, 0, stream>>>(ws);
        gemmB_kernel<<<n_paths / 4, 256, 0, stream>>>(dz, ws);
        pathCD_kernel<<<n_paths, 256, 0, stream>>>(dz, ws, out);
    } else {
        path_kernel<<<n_paths, 256, 0, stream>>>(dz, ws, out);
    }
}